// Round 10
// baseline (81.111 us; speedup 1.0000x reference)
//
#include <hip/hip_runtime.h>
#include <hip/hip_fp16.h>

#define POOLED 7
#define PP 49
#define ROI_SCALE 0.25f
#define FH 200
#define FW 304
#define FHW 60800
#define FC 256
#define RS 271           // s_out row stride (odd => conflict-free read-back)

// ---------- Pass 1: NCHW fp32 -> NHWC fp16 ----------
__global__ __launch_bounds__(256) void transpose_f16(
    const float* __restrict__ in, __half* __restrict__ out)
{
    __shared__ float tile[64][33];
    const int b   = blockIdx.z;
    const int hw0 = blockIdx.x * 32;
    const int c0  = blockIdx.y * 64;
    const int tx  = threadIdx.x;   // 0..31
    const int ty  = threadIdx.y;   // 0..7

    #pragma unroll
    for (int i = 0; i < 8; i++) {
        int c = c0 + ty + i * 8;
        tile[ty + i * 8][tx] = in[((size_t)b * FC + c) * FHW + hw0 + tx];
    }
    __syncthreads();
    #pragma unroll
    for (int i = 0; i < 4; i++) {
        int hwl = ty + i * 8;
        __half2 h = __floats2half2_rn(tile[2 * tx][hwl], tile[2 * tx + 1][hwl]);
        *reinterpret_cast<__half2*>(
            out + ((size_t)b * FHW + hwl + hw0) * FC + c0 + 2 * tx) = h;
    }
}

// ---------- Pass 2: one block (512 thr, 8 waves) per ROI. ----------
// Software pipeline (depth 2) over the wave's bins: stage k+1's 8 pixel loads
// are issued BEFORE stage k's FMAs, so each wave keeps 8-16 loads in flight
// across every wait point (no drain-to-0 per bin). Bins w..w+40 are valid for
// ALL waves, so the 7-stage pipeline is fully static with named A/B slots.
// Lane owns 8 channels (16B); half-wave split: lanes<32 use the xlo pixel,
// lanes>=32 the xhi pixel; one shfl_xor(32) merges. Output staged fp32 in LDS,
// then written fully coalesced.
__global__ __launch_bounds__(512, 4) void roi_gather_f16(
    const __half* __restrict__ f,
    const float* __restrict__ rois,
    float* __restrict__ out)
{
    __shared__ float s_out[PP * RS];   // 53,116 B -> 2 blocks/CU

    const int n    = blockIdx.x;
    const int tid  = threadIdx.x;
    const int wave = tid >> 6;
    const int lane = tid & 63;
    const int hl   = lane & 31;
    const bool hiHalf = lane >= 32;

    const float* r = rois + (size_t)n * 5;
    const int   bi = (int)r[0];
    const float x1 = r[1] * ROI_SCALE;
    const float y1 = r[2] * ROI_SCALE;
    const float bin_w = fmaxf(r[3] * ROI_SCALE - x1, 1.0f) / (float)POOLED;
    const float bin_h = fmaxf(r[4] * ROI_SCALE - y1, 1.0f) / (float)POOLED;

    const __half* base = f + (size_t)bi * (FHW * FC) + 8 * hl;
    const int c0  = 8 * hl;
    const int swz = 2 * (hl >> 2);

    // compute the 8 addresses + weights of a bin and ISSUE its 8 loads
    auto mkissue = [&](int bin, uint4* u, float* w) {
        const int ph = bin / 7;
        const int pw = bin - ph * 7;
        int   row[2][2];
        float wy[2][2];
        #pragma unroll
        for (int iy = 0; iy < 2; iy++) {
            float c = y1 + ((float)(2 * ph + iy) + 0.5f) * 0.5f * bin_h;
            float v = ((c >= -1.0f) && (c <= (float)FH)) ? 1.0f : 0.0f;
            c = fmaxf(c, 0.0f);
            int lo = (int)floorf(c);
            bool edge = (lo >= FH - 1);
            lo = min(lo, FH - 1);
            row[iy][0] = lo * FW;
            row[iy][1] = min(lo + 1, FH - 1) * FW;
            float ly = edge ? 0.0f : (c - (float)lo);
            wy[iy][0] = v * (1.0f - ly);
            wy[iy][1] = v * ly;
        }
        #pragma unroll
        for (int ix = 0; ix < 2; ix++) {
            float c = x1 + ((float)(2 * pw + ix) + 0.5f) * 0.5f * bin_w;
            float v = ((c >= -1.0f) && (c <= (float)FW)) ? 1.0f : 0.0f;
            c = fmaxf(c, 0.0f);
            int lo = (int)floorf(c);
            bool edge = (lo >= FW - 1);
            lo = min(lo, FW - 1);
            int hi = min(lo + 1, FW - 1);
            float lx = edge ? 0.0f : (c - (float)lo);
            int   px = hiHalf ? hi : lo;
            float wx = 0.25f * v * (hiHalf ? lx : (1.0f - lx));
            #pragma unroll
            for (int iy = 0; iy < 2; iy++) {
                int s0 = 4 * ix + 2 * iy;
                u[s0]     = *reinterpret_cast<const uint4*>(base + ((row[iy][0] + px) << 8));
                u[s0 + 1] = *reinterpret_cast<const uint4*>(base + ((row[iy][1] + px) << 8));
                w[s0]     = wy[iy][0] * wx;
                w[s0 + 1] = wy[iy][1] * wx;
            }
        }
    };

    // consume a bin's 8 loaded pixels, merge halves, store to LDS
    auto compute = [&](int bin, const uint4* u, const float* w) {
        float acc[8] = {0.f, 0.f, 0.f, 0.f, 0.f, 0.f, 0.f, 0.f};
        #pragma unroll
        for (int s = 0; s < 8; s++) {
            const __half2* h = reinterpret_cast<const __half2*>(&u[s]);
            float ws = w[s];
            #pragma unroll
            for (int j = 0; j < 4; j++) {
                float2 fj = __half22float2(h[j]);
                acc[2 * j]     += ws * fj.x;
                acc[2 * j + 1] += ws * fj.y;
            }
        }
        #pragma unroll
        for (int k = 0; k < 8; k++)
            acc[k] += __shfl_xor(acc[k], 32, 64);
        if (!hiHalf) {
            float* so = s_out + bin * RS + c0 + swz;
            #pragma unroll
            for (int k = 0; k < 8; k++)
                so[k] = acc[k];
        }
    };

    uint4 uA[8], uB[8];
    float wA[8], wB[8];

    // 7-stage static pipeline: bins w, w+8, ..., w+40 valid for all waves;
    // bin 48 (stage 6) only for wave 0.
    mkissue(wave, uA, wA);

    mkissue(wave + 8,  uB, wB);  compute(wave,      uA, wA);
    mkissue(wave + 16, uA, wA);  compute(wave + 8,  uB, wB);
    mkissue(wave + 24, uB, wB);  compute(wave + 16, uA, wA);
    mkissue(wave + 32, uA, wA);  compute(wave + 24, uB, wB);
    mkissue(wave + 40, uB, wB);  compute(wave + 32, uA, wA);
    if (wave == 0) { mkissue(48, uA, wA); }
    compute(wave + 40, uB, wB);
    if (wave == 0) { compute(48, uA, wA); }

    __syncthreads();

    // fully coalesced write: out[n][c][bin], consecutive tid -> consecutive addr
    float* ob = out + (size_t)n * (FC * PP);
    for (int i = tid; i < FC * PP; i += 512) {
        int c = i / PP;
        int b = i - c * PP;
        ob[i] = s_out[b * RS + c + 2 * (c >> 5)];
    }
}

// ---------- Fallback (round-1 kernel) if workspace too small ----------
__global__ __launch_bounds__(256) void roi_align_fallback(
    const float* __restrict__ feat,
    const float* __restrict__ rois,
    float* __restrict__ out,
    int C, int H, int W, int N)
{
    int idx = blockIdx.x * blockDim.x + threadIdx.x;
    int total = N * C * PP;
    if (idx >= total) return;

    int pw = idx % POOLED;
    int ph = (idx / POOLED) % POOLED;
    int c  = (idx / PP) % C;
    int n  = idx / (PP * C);

    const float* r = rois + (size_t)n * 5;
    int   b  = (int)r[0];
    float x1 = r[1] * ROI_SCALE;
    float y1 = r[2] * ROI_SCALE;
    float bin_w = fmaxf(r[3] * ROI_SCALE - x1, 1.0f) / (float)POOLED;
    float bin_h = fmaxf(r[4] * ROI_SCALE - y1, 1.0f) / (float)POOLED;

    const float* fc = feat + ((size_t)b * C + c) * (size_t)(H * W);

    float acc = 0.0f;
    #pragma unroll
    for (int iy = 0; iy < 2; iy++) {
        float yy = y1 + ((float)(ph * 2 + iy) + 0.5f) * bin_h * 0.5f;
        bool  vy = (yy >= -1.0f) && (yy <= (float)H);
        float cy = fmaxf(yy, 0.0f);
        int   ylo = (int)floorf(cy);
        bool  ey = (ylo >= H - 1);
        ylo = min(ylo, H - 1);
        int   yhi = min(ylo + 1, H - 1);
        if (ey) cy = (float)ylo;
        float ly = cy - (float)ylo, hy = 1.0f - ly;

        #pragma unroll
        for (int ix = 0; ix < 2; ix++) {
            float xx = x1 + ((float)(pw * 2 + ix) + 0.5f) * bin_w * 0.5f;
            bool  vx = (xx >= -1.0f) && (xx <= (float)W);
            float cx = fmaxf(xx, 0.0f);
            int   xlo = (int)floorf(cx);
            bool  ex = (xlo >= W - 1);
            xlo = min(xlo, W - 1);
            int   xhi = min(xlo + 1, W - 1);
            if (ex) cx = (float)xlo;
            float lx = cx - (float)xlo, hx = 1.0f - lx;

            if (vy && vx) {
                float v11 = fc[(size_t)ylo * W + xlo];
                float v12 = fc[(size_t)ylo * W + xhi];
                float v21 = fc[(size_t)yhi * W + xlo];
                float v22 = fc[(size_t)yhi * W + xhi];
                acc += hy * (hx * v11 + lx * v12) + ly * (hx * v21 + lx * v22);
            }
        }
    }
    out[idx] = acc * 0.25f;
}

extern "C" void kernel_launch(void* const* d_in, const int* in_sizes, int n_in,
                              void* d_out, int out_size, void* d_ws, size_t ws_size,
                              hipStream_t stream) {
    const float* feat = (const float*)d_in[0];
    const float* rois = (const float*)d_in[1];
    float* out = (float*)d_out;

    const int N = in_sizes[1] / 5;
    const int B = in_sizes[0] / (FC * FHW);

    const size_t need = (size_t)B * FHW * FC * sizeof(__half);
    if (ws_size >= need) {
        __half* f16 = (__half*)d_ws;
        transpose_f16<<<dim3(FHW / 32, FC / 64, B), dim3(32, 8), 0, stream>>>(feat, f16);
        roi_gather_f16<<<N, 512, 0, stream>>>(f16, rois, out);
    } else {
        int total = N * FC * PP;
        roi_align_fallback<<<(total + 255) / 256, 256, 0, stream>>>(feat, rois, out, FC, FH, FW, N);
    }
}